// Round 2
// baseline (447.933 us; speedup 1.0000x reference)
//
#include <hip/hip_runtime.h>

// GumbelSlotSelector via MFMA: layer1 (524288x64x128 fp32 GEMM) as 6-term
// exact 3xbf16-split MFMA; layer2 + gumbel + ballot fixup fused per-wave.
// This revision fixes load duty-cycle (measured 45% of achievable BW):
// slots are staged via ASYNC global_load_lds into wave-private LDS chunks,
// double-buffered at half-ks-step granularity (4 KB/wave), with counted
// s_waitcnt vmcnt(4/6) so the next chunk is ALWAYS in flight during
// convert+MFMA. vmcnt is never drained to 0 in the loop; no __syncthreads
// in the loop (all staging is wave-private). Compute order is bit-identical
// to the previous passing kernel.

typedef __attribute__((ext_vector_type(8))) short bf16x8;
typedef __attribute__((ext_vector_type(4))) float f32x4;

constexpr int NROWS = 8192 * 64;   // 524288
constexpr int D = 128;

typedef const __attribute__((address_space(1))) unsigned int gbl_u32;
typedef __attribute__((address_space(3))) unsigned int lds_u32;

__device__ __forceinline__ void dma16(const float* g, float* l) {
    // async global->LDS, 16 B/lane; LDS dest = uniform base + lane*16
    __builtin_amdgcn_global_load_lds((gbl_u32*)g, (lds_u32*)l, 16, 0, 0);
}

__device__ __forceinline__ void split3(float x, unsigned& h1, unsigned& h2, unsigned& h3) {
    unsigned ux = __float_as_uint(x);
    h1 = ux & 0xFFFF0000u;                       // top 8 mantissa bits
    float r = x - __uint_as_float(h1);           // exact
    h2 = __float_as_uint(r) & 0xFFFF0000u;       // next 8
    float r2 = r - __uint_as_float(h2);          // exact
    h3 = __float_as_uint(r2) & 0xFFFF0000u;      // remaining bits (exact)
}

__global__ __launch_bounds__(512, 2)
void gumbel_slot_mfma(const float* __restrict__ slots,
                      const float* __restrict__ gumbel_u,
                      const float* __restrict__ fix_u,
                      const float* __restrict__ W1,
                      const float* __restrict__ b1,
                      const float* __restrict__ W2,
                      const float* __restrict__ b2,
                      float* __restrict__ out)
{
    __shared__ __align__(16) unsigned short wt[3 * 64 * 128];  // 48 KB W1 splits
    __shared__ __align__(16) float red[8][16][16][2];          // 16 KB epilogue
    __shared__ __align__(16) float stg[2][8][4][64][4];        // 64 KB async stage

    const int tid  = threadIdx.x;
    const int wv   = tid >> 6;        // wave 0..7
    const int lane = tid & 63;
    const int quad = lane >> 4;       // 0..3
    const int col  = lane & 15;       // 0..15

    const int tile0 = blockIdx.x * 4;               // 4 consecutive tiles/block

    // ---- prologue: async-stage chunk (t=0, ks=0, h=0) into stg[0] ----
    {
        const int rowW = tile0 * 512 + wv * 64;
#pragma unroll
        for (int i = 0; i < 4; ++i) {
            const int mt = i >> 1, q16 = i & 1;
            dma16(slots + (size_t)(rowW + mt * 16 + col) * D + quad * 8 + q16 * 4,
                  &stg[0][wv][i][0][0]);
        }
    }

    // ---- one-time: split W1 into 3 bf16 planes, transposed [j][d] ----
#pragma unroll
    for (int i = 0; i < 16; ++i) {
        const int e = i * 512 + tid;          // 8192 elements, coalesced
        const int d = e >> 6, j = e & 63;
        unsigned h1, h2, h3;
        split3(W1[e], h1, h2, h3);
        const int chunk = (d >> 3) ^ (j & 15);           // 16B-chunk swizzle
        const int idx = j * 128 + chunk * 8 + (d & 7);
        wt[idx]             = (unsigned short)(h1 >> 16);
        wt[idx + 8192]      = (unsigned short)(h2 >> 16);
        wt[idx + 16384]     = (unsigned short)(h3 >> 16);
    }

    // per-lane constants + ALL gumbel pairs, loaded pre-barrier so the
    // barrier's vmcnt(0) drain absorbs them (loop vmcnt accounting stays clean)
    float  b1v[4];
    float2 w2v[4];
#pragma unroll
    for (int nt = 0; nt < 4; ++nt) {
        b1v[nt] = b1[nt * 16 + col];
        w2v[nt] = *(const float2*)(W2 + (size_t)(nt * 16 + col) * 2);
    }
    const float2 b2v = *(const float2*)b2;
    float2 gu0, gu1, gu2, gu3;
    {
        const size_t rb = (size_t)(tile0 * 512 + wv * 64 + lane);
        gu0 = *(const float2*)(gumbel_u + (rb         ) * 2);
        gu1 = *(const float2*)(gumbel_u + (rb +  512  ) * 2);
        gu2 = *(const float2*)(gumbel_u + (rb + 1024  ) * 2);
        gu3 = *(const float2*)(gumbel_u + (rb + 1536  ) * 2);
    }

    __syncthreads();   // wt ready; also drains prologue DMA + all preamble loads

#pragma unroll 1
    for (int t = 0; t < 4; ++t) {
        const int rowW = (tile0 + t) * 512 + wv * 64;    // this wave's 64 rows
        const int r    = rowW + lane;

        f32x4 acc[4][4];
#pragma unroll
        for (int mt = 0; mt < 4; ++mt)
#pragma unroll
            for (int nt = 0; nt < 4; ++nt)
                acc[mt][nt] = f32x4{b1v[nt], b1v[nt], b1v[nt], b1v[nt]};

#pragma unroll
        for (int ks = 0; ks < 4; ++ks) {                 // k0 = ks*32
            bf16x8 bq1[4], bq2[4], bq3[4];               // live across both halves
#pragma unroll
            for (int h = 0; h < 2; ++h) {                // half-step: mt pair {2h,2h+1}
                // ---- issue next chunk's 4 DMAs (into the other buffer) ----
                const int  nh   = h ^ 1;
                const int  nks  = (h == 1) ? ((ks + 1) & 3) : ks;
                const bool bump = (ks == 3 && h == 1);   // crosses into next tile
                if (!bump || t < 3) {
                    const int rowN = (tile0 + t + (bump ? 1 : 0)) * 512 + wv * 64;
#pragma unroll
                    for (int i = 0; i < 4; ++i) {
                        const int mt = 2 * nh + (i >> 1), q16 = i & 1;
                        dma16(slots + (size_t)(rowN + mt * 16 + col) * D
                                    + nks * 32 + quad * 8 + q16 * 4,
                              &stg[nh][wv][i][0][0]);
                    }
                }

                // ---- counted wait: current chunk arrived, next stays in flight.
                // After chunk (t,ks,h) in program order: 4 DMAs (next chunk),
                // +2 stores at tile boundary. Extra compiler vm ops only make
                // the wait stricter (vmcnt retires in order) -> safe.
                if (ks == 0 && h == 0) {
                    if (t == 0) { asm volatile("s_waitcnt vmcnt(4)" ::: "memory"); }
                    else        { asm volatile("s_waitcnt vmcnt(6)" ::: "memory"); }
                } else if (ks == 3 && h == 1) {
                    if (t < 3)  { asm volatile("s_waitcnt vmcnt(4)" ::: "memory"); }
                    else        { asm volatile("s_waitcnt vmcnt(0)" ::: "memory"); }
                } else          { asm volatile("s_waitcnt vmcnt(4)" ::: "memory"); }
                __builtin_amdgcn_sched_barrier(0);

                // ---- read own staged chunk back (linear, conflict-free) ----
                f32x4 v[4];
#pragma unroll
                for (int i = 0; i < 4; ++i)
                    v[i] = *(const f32x4*)&stg[h][wv][i][lane][0];

                // ---- B fragments: read once per ks (h==0), reuse at h==1 ----
                if (h == 0) {
#pragma unroll
                    for (int nt = 0; nt < 4; ++nt) {
                        const int j = nt * 16 + col;
                        const int chunk = (ks * 4 + quad) ^ col;
                        const unsigned short* wp = &wt[j * 128 + chunk * 8];
                        bq1[nt] = *(const bf16x8*)(wp);
                        bq2[nt] = *(const bf16x8*)(wp + 8192);
                        bq3[nt] = *(const bf16x8*)(wp + 16384);
                    }
                }

                // ---- convert mt pair to 3-split A fragments (bit-identical) ----
                bf16x8 a1[2], a2[2], a3[2];
#pragma unroll
                for (int mp = 0; mp < 2; ++mp) {
                    const float xs[8] = {v[2*mp][0], v[2*mp][1], v[2*mp][2], v[2*mp][3],
                                         v[2*mp+1][0], v[2*mp+1][1], v[2*mp+1][2], v[2*mp+1][3]};
                    union { int i[4]; bf16x8 vv; } u1, u2, u3;
#pragma unroll
                    for (int p = 0; p < 4; ++p) {
                        unsigned xh1, xh2, xh3, yh1, yh2, yh3;
                        split3(xs[2 * p],     xh1, xh2, xh3);
                        split3(xs[2 * p + 1], yh1, yh2, yh3);
                        u1.i[p] = (int)((xh1 >> 16) | yh1);  // [k even | k odd]
                        u2.i[p] = (int)((xh2 >> 16) | yh2);
                        u3.i[p] = (int)((xh3 >> 16) | yh3);
                    }
                    a1[mp] = u1.vv; a2[mp] = u2.vv; a3[mp] = u3.vv;
                }

                // ---- MFMA: same per-chain accumulation order as before ----
                __builtin_amdgcn_s_setprio(1);
#pragma unroll
                for (int nt = 0; nt < 4; ++nt) {
#pragma unroll
                    for (int mp = 0; mp < 2; ++mp) {
                        const int mt = 2 * h + mp;
                        f32x4 c = acc[mt][nt];
                        c = __builtin_amdgcn_mfma_f32_16x16x32_bf16(a1[mp], bq1[nt], c, 0, 0, 0);
                        c = __builtin_amdgcn_mfma_f32_16x16x32_bf16(a2[mp], bq1[nt], c, 0, 0, 0);
                        c = __builtin_amdgcn_mfma_f32_16x16x32_bf16(a1[mp], bq2[nt], c, 0, 0, 0);
                        c = __builtin_amdgcn_mfma_f32_16x16x32_bf16(a2[mp], bq2[nt], c, 0, 0, 0);
                        c = __builtin_amdgcn_mfma_f32_16x16x32_bf16(a1[mp], bq3[nt], c, 0, 0, 0);
                        c = __builtin_amdgcn_mfma_f32_16x16x32_bf16(a3[mp], bq1[nt], c, 0, 0, 0);
                        acc[mt][nt] = c;
                    }
                }
                __builtin_amdgcn_s_setprio(0);
            }
        }

        // ---- epilogue: layer2 partials + per-row transpose via LDS ----
        // red[wv] is WAVE-PRIVATE; wave LDS ops are in-order -> compile fence only.
        float fl0 = 0.f, fl1 = 0.f;
#pragma unroll 1
        for (int mt = 0; mt < 4; ++mt) {
#pragma unroll
            for (int reg = 0; reg < 4; ++reg) {
                float p0 = 0.f, p1 = 0.f;
#pragma unroll
                for (int nt = 0; nt < 4; ++nt) {
                    const float h = fmaxf(acc[mt][nt][reg], 0.f);
                    p0 = fmaf(h, w2v[nt].x, p0);
                    p1 = fmaf(h, w2v[nt].y, p1);
                }
                const int rl = quad * 4 + reg;
                *(float2*)&red[wv][rl][col ^ rl][0] = make_float2(p0, p1);
            }
            __builtin_amdgcn_wave_barrier();
            if (quad == mt) {
                const int rl = col;
                float s0 = 0.f, s1 = 0.f;
#pragma unroll
                for (int c = 0; c < 16; ++c) {
                    const float2 vv = *(const float2*)&red[wv][rl][c ^ rl][0];
                    s0 += vv.x; s1 += vv.y;
                }
                fl0 = s0; fl1 = s1;
            }
            __builtin_amdgcn_wave_barrier();
        }
        const float l0 = fl0 + b2v.x;
        const float l1 = fl1 + b2v.y;

        // ---- gumbel decision + keep prob ----
        const float2 guv = (t == 0) ? gu0 : ((t == 1) ? gu1 : ((t == 2) ? gu2 : gu3));
        const float lo = 1e-10f, hi = (float)(1.0 - 1e-7);
        const float u0 = fminf(fmaxf(guv.x, lo), hi);
        const float u1 = fminf(fmaxf(guv.y, lo), hi);
        const float g0 = -logf(-logf(u0));
        const float g1 = -logf(-logf(u1));
        float dec = ((l1 + g1) > (l0 + g0)) ? 1.0f : 0.0f;

        const float m  = fmaxf(l0, l1);
        const float e0 = expf(l0 - m), e1 = expf(l1 - m);
        const float keep = e1 / (e0 + e1);

        // ensure-minimum: this wave's 64 lanes == one b's 64 slots
        const unsigned long long act = __ballot(dec != 0.0f);
        if (act == 0ull) {
            float v = fix_u[r];
            int  idx = lane;
#pragma unroll
            for (int off = 32; off > 0; off >>= 1) {
                const float ov  = __shfl_xor(v, off, 64);
                const int  oidx = __shfl_xor(idx, off, 64);
                if (ov > v || (ov == v && oidx < idx)) { v = ov; idx = oidx; }
            }
            if (lane == idx) dec = 1.0f;
        }

        out[r] = dec;
        out[NROWS + r] = keep;
    }
}

extern "C" void kernel_launch(void* const* d_in, const int* in_sizes, int n_in,
                              void* d_out, int out_size, void* d_ws, size_t ws_size,
                              hipStream_t stream)
{
    const float* slots  = (const float*)d_in[0];
    const float* gumbel = (const float*)d_in[1];
    const float* fixu   = (const float*)d_in[2];
    const float* W1     = (const float*)d_in[3];
    const float* b1     = (const float*)d_in[4];
    const float* W2     = (const float*)d_in[5];
    const float* b2     = (const float*)d_in[6];
    float* out = (float*)d_out;

    gumbel_slot_mfma<<<256, 512, 0, stream>>>(
        slots, gumbel, fixu, W1, b1, W2, b2, out);
}

// Round 3
// 443.335 us; speedup vs baseline: 1.0104x; 1.0104x over previous
//
#include <hip/hip_runtime.h>

// GumbelSlotSelector via MFMA: layer1 (524288x64x128 fp32 GEMM) as 6-term
// exact 3xbf16-split MFMA; layer2 + gumbel + ballot fixup fused per-wave.
// Async global_load_lds staging with counted vmcnt (proven correct + 71% BW
// in the previous round) -- this revision removes the register spills that
// inflated HBM traffic 3x: no persistent bq/v arrays; B-fragments are
// re-read from LDS per-nt (12 live VGPRs), A-conversion is transient.
// Compute order per accumulator chain is bit-identical to the passing kernel.

typedef __attribute__((ext_vector_type(8))) short bf16x8;
typedef __attribute__((ext_vector_type(4))) float f32x4;

constexpr int NROWS = 8192 * 64;   // 524288
constexpr int D = 128;

typedef const __attribute__((address_space(1))) unsigned int gbl_u32;
typedef __attribute__((address_space(3))) unsigned int lds_u32;

__device__ __forceinline__ void dma16(const float* g, float* l) {
    // async global->LDS, 16 B/lane; LDS dest = uniform base + lane*16
    __builtin_amdgcn_global_load_lds((gbl_u32*)g, (lds_u32*)l, 16, 0, 0);
}

__device__ __forceinline__ void split3(float x, unsigned& h1, unsigned& h2, unsigned& h3) {
    unsigned ux = __float_as_uint(x);
    h1 = ux & 0xFFFF0000u;                       // top 8 mantissa bits
    float r = x - __uint_as_float(h1);           // exact
    h2 = __float_as_uint(r) & 0xFFFF0000u;       // next 8
    float r2 = r - __uint_as_float(h2);          // exact
    h3 = __float_as_uint(r2) & 0xFFFF0000u;      // remaining bits (exact)
}

__global__ __launch_bounds__(512, 2)
void gumbel_slot_mfma(const float* __restrict__ slots,
                      const float* __restrict__ gumbel_u,
                      const float* __restrict__ fix_u,
                      const float* __restrict__ W1,
                      const float* __restrict__ b1,
                      const float* __restrict__ W2,
                      const float* __restrict__ b2,
                      float* __restrict__ out)
{
    __shared__ __align__(16) unsigned short wt[3 * 64 * 128];  // 48 KB W1 splits
    __shared__ __align__(16) float red[8][16][16][2];          // 16 KB epilogue
    __shared__ __align__(16) float stg[2][8][4][64][4];        // 64 KB async stage

    const int tid  = threadIdx.x;
    const int wv   = tid >> 6;        // wave 0..7
    const int lane = tid & 63;
    const int quad = lane >> 4;       // 0..3
    const int col  = lane & 15;       // 0..15

    const int tile0 = blockIdx.x * 4;               // 4 consecutive tiles/block

    // ---- prologue: async-stage chunk (t=0, ks=0, h=0) into stg[0] ----
    {
        const int rowW = tile0 * 512 + wv * 64;
#pragma unroll
        for (int i = 0; i < 4; ++i) {
            const int mt = i >> 1, q16 = i & 1;
            dma16(slots + (size_t)(rowW + mt * 16 + col) * D + quad * 8 + q16 * 4,
                  &stg[0][wv][i][0][0]);
        }
    }

    // ---- one-time: split W1 into 3 bf16 planes, transposed [j][d] ----
#pragma unroll
    for (int i = 0; i < 16; ++i) {
        const int e = i * 512 + tid;          // 8192 elements, coalesced
        const int d = e >> 6, j = e & 63;
        unsigned h1, h2, h3;
        split3(W1[e], h1, h2, h3);
        const int chunk = (d >> 3) ^ (j & 15);           // 16B-chunk swizzle
        const int idx = j * 128 + chunk * 8 + (d & 7);
        wt[idx]             = (unsigned short)(h1 >> 16);
        wt[idx + 8192]      = (unsigned short)(h2 >> 16);
        wt[idx + 16384]     = (unsigned short)(h3 >> 16);
    }

    // per-lane constants + ALL gumbel pairs, loaded pre-barrier so the
    // barrier's drain absorbs them (loop vmcnt accounting stays clean)
    float  b1v[4];
    float2 w2v[4];
#pragma unroll
    for (int nt = 0; nt < 4; ++nt) {
        b1v[nt] = b1[nt * 16 + col];
        w2v[nt] = *(const float2*)(W2 + (size_t)(nt * 16 + col) * 2);
    }
    const float2 b2v = *(const float2*)b2;
    float2 gu0, gu1, gu2, gu3;
    {
        const size_t rb = (size_t)(tile0 * 512 + wv * 64 + lane);
        gu0 = *(const float2*)(gumbel_u + (rb         ) * 2);
        gu1 = *(const float2*)(gumbel_u + (rb +  512  ) * 2);
        gu2 = *(const float2*)(gumbel_u + (rb + 1024  ) * 2);
        gu3 = *(const float2*)(gumbel_u + (rb + 1536  ) * 2);
    }

    __syncthreads();   // wt ready; also drains prologue DMA + all preamble loads

#pragma unroll 1
    for (int t = 0; t < 4; ++t) {
        const int rowW = (tile0 + t) * 512 + wv * 64;    // this wave's 64 rows
        const int r    = rowW + lane;

        f32x4 acc[4][4];
#pragma unroll
        for (int mt = 0; mt < 4; ++mt)
#pragma unroll
            for (int nt = 0; nt < 4; ++nt)
                acc[mt][nt] = f32x4{b1v[nt], b1v[nt], b1v[nt], b1v[nt]};

#pragma unroll
        for (int ks = 0; ks < 4; ++ks) {                 // k0 = ks*32
#pragma unroll
            for (int h = 0; h < 2; ++h) {                // half-step: mt pair {2h,2h+1}
                // ---- issue next chunk's 4 DMAs (into the other buffer) ----
                const int  nh   = h ^ 1;
                const int  nks  = (h == 1) ? ((ks + 1) & 3) : ks;
                const bool bump = (ks == 3 && h == 1);   // crosses into next tile
                if (!bump || t < 3) {
                    const int rowN = (tile0 + t + (bump ? 1 : 0)) * 512 + wv * 64;
#pragma unroll
                    for (int i = 0; i < 4; ++i) {
                        const int mt = 2 * nh + (i >> 1), q16 = i & 1;
                        dma16(slots + (size_t)(rowN + mt * 16 + col) * D
                                    + nks * 32 + quad * 8 + q16 * 4,
                              &stg[nh][wv][i][0][0]);
                    }
                }

                // ---- counted wait: current chunk arrived, next stays in flight.
                if (ks == 0 && h == 0) {
                    if (t == 0) { asm volatile("s_waitcnt vmcnt(4)" ::: "memory"); }
                    else        { asm volatile("s_waitcnt vmcnt(6)" ::: "memory"); }
                } else if (ks == 3 && h == 1) {
                    if (t < 3)  { asm volatile("s_waitcnt vmcnt(4)" ::: "memory"); }
                    else        { asm volatile("s_waitcnt vmcnt(0)" ::: "memory"); }
                } else          { asm volatile("s_waitcnt vmcnt(4)" ::: "memory"); }
                __builtin_amdgcn_sched_barrier(0);

                // ---- read own staged chunk + convert (transient registers) ----
                bf16x8 a1[2], a2[2], a3[2];
#pragma unroll
                for (int mp = 0; mp < 2; ++mp) {
                    const f32x4 va = *(const f32x4*)&stg[h][wv][2 * mp    ][lane][0];
                    const f32x4 vb = *(const f32x4*)&stg[h][wv][2 * mp + 1][lane][0];
                    const float xs[8] = {va[0], va[1], va[2], va[3],
                                         vb[0], vb[1], vb[2], vb[3]};
                    union { int i[4]; bf16x8 vv; } u1, u2, u3;
#pragma unroll
                    for (int p = 0; p < 4; ++p) {
                        unsigned xh1, xh2, xh3, yh1, yh2, yh3;
                        split3(xs[2 * p],     xh1, xh2, xh3);
                        split3(xs[2 * p + 1], yh1, yh2, yh3);
                        u1.i[p] = (int)((xh1 >> 16) | yh1);  // [k even | k odd]
                        u2.i[p] = (int)((xh2 >> 16) | yh2);
                        u3.i[p] = (int)((xh3 >> 16) | yh3);
                    }
                    a1[mp] = u1.vv; a2[mp] = u2.vv; a3[mp] = u3.vv;
                }

                // ---- MFMA: B fragments re-read per-nt (12 live VGPRs only);
                // per-chain accumulation order identical to previous kernel ----
                __builtin_amdgcn_s_setprio(1);
#pragma unroll
                for (int nt = 0; nt < 4; ++nt) {
                    const int j = nt * 16 + col;
                    const int chunk = (ks * 4 + quad) ^ col;
                    const unsigned short* wp = &wt[j * 128 + chunk * 8];
                    const bf16x8 bq1 = *(const bf16x8*)(wp);
                    const bf16x8 bq2 = *(const bf16x8*)(wp + 8192);
                    const bf16x8 bq3 = *(const bf16x8*)(wp + 16384);
#pragma unroll
                    for (int mp = 0; mp < 2; ++mp) {
                        const int mt = 2 * h + mp;
                        f32x4 c = acc[mt][nt];
                        c = __builtin_amdgcn_mfma_f32_16x16x32_bf16(a1[mp], bq1, c, 0, 0, 0);
                        c = __builtin_amdgcn_mfma_f32_16x16x32_bf16(a2[mp], bq1, c, 0, 0, 0);
                        c = __builtin_amdgcn_mfma_f32_16x16x32_bf16(a1[mp], bq2, c, 0, 0, 0);
                        c = __builtin_amdgcn_mfma_f32_16x16x32_bf16(a2[mp], bq2, c, 0, 0, 0);
                        c = __builtin_amdgcn_mfma_f32_16x16x32_bf16(a1[mp], bq3, c, 0, 0, 0);
                        c = __builtin_amdgcn_mfma_f32_16x16x32_bf16(a3[mp], bq1, c, 0, 0, 0);
                        acc[mt][nt] = c;
                    }
                }
                __builtin_amdgcn_s_setprio(0);
            }
        }

        // ---- epilogue: layer2 partials + per-row transpose via LDS ----
        // red[wv] is WAVE-PRIVATE; wave LDS ops are in-order -> compile fence only.
        float fl0 = 0.f, fl1 = 0.f;
#pragma unroll 1
        for (int mt = 0; mt < 4; ++mt) {
#pragma unroll
            for (int reg = 0; reg < 4; ++reg) {
                float p0 = 0.f, p1 = 0.f;
#pragma unroll
                for (int nt = 0; nt < 4; ++nt) {
                    const float h = fmaxf(acc[mt][nt][reg], 0.f);
                    p0 = fmaf(h, w2v[nt].x, p0);
                    p1 = fmaf(h, w2v[nt].y, p1);
                }
                const int rl = quad * 4 + reg;
                *(float2*)&red[wv][rl][col ^ rl][0] = make_float2(p0, p1);
            }
            __builtin_amdgcn_wave_barrier();
            if (quad == mt) {
                const int rl = col;
                float s0 = 0.f, s1 = 0.f;
#pragma unroll
                for (int c = 0; c < 16; ++c) {
                    const float2 vv = *(const float2*)&red[wv][rl][c ^ rl][0];
                    s0 += vv.x; s1 += vv.y;
                }
                fl0 = s0; fl1 = s1;
            }
            __builtin_amdgcn_wave_barrier();
        }
        const float l0 = fl0 + b2v.x;
        const float l1 = fl1 + b2v.y;

        // ---- gumbel decision + keep prob ----
        const float2 guv = (t == 0) ? gu0 : ((t == 1) ? gu1 : ((t == 2) ? gu2 : gu3));
        const float lo = 1e-10f, hi = (float)(1.0 - 1e-7);
        const float u0 = fminf(fmaxf(guv.x, lo), hi);
        const float u1 = fminf(fmaxf(guv.y, lo), hi);
        const float g0 = -logf(-logf(u0));
        const float g1 = -logf(-logf(u1));
        float dec = ((l1 + g1) > (l0 + g0)) ? 1.0f : 0.0f;

        const float m  = fmaxf(l0, l1);
        const float e0 = expf(l0 - m), e1 = expf(l1 - m);
        const float keep = e1 / (e0 + e1);

        // ensure-minimum: this wave's 64 lanes == one b's 64 slots
        const unsigned long long act = __ballot(dec != 0.0f);
        if (act == 0ull) {
            float v = fix_u[r];
            int  idx = lane;
#pragma unroll
            for (int off = 32; off > 0; off >>= 1) {
                const float ov  = __shfl_xor(v, off, 64);
                const int  oidx = __shfl_xor(idx, off, 64);
                if (ov > v || (ov == v && oidx < idx)) { v = ov; idx = oidx; }
            }
            if (lane == idx) dec = 1.0f;
        }

        out[r] = dec;
        out[NROWS + r] = keep;
    }
}

extern "C" void kernel_launch(void* const* d_in, const int* in_sizes, int n_in,
                              void* d_out, int out_size, void* d_ws, size_t ws_size,
                              hipStream_t stream)
{
    const float* slots  = (const float*)d_in[0];
    const float* gumbel = (const float*)d_in[1];
    const float* fixu   = (const float*)d_in[2];
    const float* W1     = (const float*)d_in[3];
    const float* b1     = (const float*)d_in[4];
    const float* W2     = (const float*)d_in[5];
    const float* b2     = (const float*)d_in[6];
    float* out = (float*)d_out;

    gumbel_slot_mfma<<<256, 512, 0, stream>>>(
        slots, gumbel, fixu, W1, b1, W2, b2, out);
}

// Round 4
// 374.948 us; speedup vs baseline: 1.1947x; 1.1824x over previous
//
#include <hip/hip_runtime.h>

// GumbelSlotSelector via MFMA: layer1 (524288x64x128 fp32 GEMM) as 6-term
// exact 3xbf16-split MFMA; layer2 + gumbel + ballot fixup fused per-wave.
// Async global_load_lds staging, double-buffered at half-ks-step granularity,
// counted s_waitcnt vmcnt(4/6) so a chunk is always in flight during compute.
//
// THIS REVISION: fix the scratch demotion of acc[4][4]. The epilogue's
// `#pragma unroll 1` mt-loop indexed acc with a RUNTIME mt -> the whole
// accumulator array lived in scratch (observed: 601 MB WRITE_SIZE vs 4 MB
// expected, VGPR_Count=104). Epilogue mt-loop is now fully unrolled so every
// acc access is compile-time-indexed. No other change; compute order is
// bit-identical to the passing kernel.

typedef __attribute__((ext_vector_type(8))) short bf16x8;
typedef __attribute__((ext_vector_type(4))) float f32x4;

constexpr int NROWS = 8192 * 64;   // 524288
constexpr int D = 128;

typedef const __attribute__((address_space(1))) unsigned int gbl_u32;
typedef __attribute__((address_space(3))) unsigned int lds_u32;

__device__ __forceinline__ void dma16(const float* g, float* l) {
    // async global->LDS, 16 B/lane; LDS dest = uniform base + lane*16
    __builtin_amdgcn_global_load_lds((gbl_u32*)g, (lds_u32*)l, 16, 0, 0);
}

__device__ __forceinline__ void split3(float x, unsigned& h1, unsigned& h2, unsigned& h3) {
    unsigned ux = __float_as_uint(x);
    h1 = ux & 0xFFFF0000u;                       // top 8 mantissa bits
    float r = x - __uint_as_float(h1);           // exact
    h2 = __float_as_uint(r) & 0xFFFF0000u;       // next 8
    float r2 = r - __uint_as_float(h2);          // exact
    h3 = __float_as_uint(r2) & 0xFFFF0000u;      // remaining bits (exact)
}

__global__ __launch_bounds__(512, 2)
void gumbel_slot_mfma(const float* __restrict__ slots,
                      const float* __restrict__ gumbel_u,
                      const float* __restrict__ fix_u,
                      const float* __restrict__ W1,
                      const float* __restrict__ b1,
                      const float* __restrict__ W2,
                      const float* __restrict__ b2,
                      float* __restrict__ out)
{
    __shared__ __align__(16) unsigned short wt[3 * 64 * 128];  // 48 KB W1 splits
    __shared__ __align__(16) float red[8][16][16][2];          // 16 KB epilogue
    __shared__ __align__(16) float stg[2][8][4][64][4];        // 64 KB async stage

    const int tid  = threadIdx.x;
    const int wv   = tid >> 6;        // wave 0..7
    const int lane = tid & 63;
    const int quad = lane >> 4;       // 0..3
    const int col  = lane & 15;       // 0..15

    const int tile0 = blockIdx.x * 4;               // 4 consecutive tiles/block

    // ---- prologue: async-stage chunk (t=0, ks=0, h=0) into stg[0] ----
    {
        const int rowW = tile0 * 512 + wv * 64;
#pragma unroll
        for (int i = 0; i < 4; ++i) {
            const int mt = i >> 1, q16 = i & 1;
            dma16(slots + (size_t)(rowW + mt * 16 + col) * D + quad * 8 + q16 * 4,
                  &stg[0][wv][i][0][0]);
        }
    }

    // ---- one-time: split W1 into 3 bf16 planes, transposed [j][d] ----
#pragma unroll
    for (int i = 0; i < 16; ++i) {
        const int e = i * 512 + tid;          // 8192 elements, coalesced
        const int d = e >> 6, j = e & 63;
        unsigned h1, h2, h3;
        split3(W1[e], h1, h2, h3);
        const int chunk = (d >> 3) ^ (j & 15);           // 16B-chunk swizzle
        const int idx = j * 128 + chunk * 8 + (d & 7);
        wt[idx]             = (unsigned short)(h1 >> 16);
        wt[idx + 8192]      = (unsigned short)(h2 >> 16);
        wt[idx + 16384]     = (unsigned short)(h3 >> 16);
    }

    // per-lane constants + ALL gumbel pairs, loaded pre-barrier so the
    // barrier's drain absorbs them (loop vmcnt accounting stays clean)
    float  b1v[4];
    float2 w2v[4];
#pragma unroll
    for (int nt = 0; nt < 4; ++nt) {
        b1v[nt] = b1[nt * 16 + col];
        w2v[nt] = *(const float2*)(W2 + (size_t)(nt * 16 + col) * 2);
    }
    const float2 b2v = *(const float2*)b2;
    float2 gu0, gu1, gu2, gu3;
    {
        const size_t rb = (size_t)(tile0 * 512 + wv * 64 + lane);
        gu0 = *(const float2*)(gumbel_u + (rb         ) * 2);
        gu1 = *(const float2*)(gumbel_u + (rb +  512  ) * 2);
        gu2 = *(const float2*)(gumbel_u + (rb + 1024  ) * 2);
        gu3 = *(const float2*)(gumbel_u + (rb + 1536  ) * 2);
    }

    __syncthreads();   // wt ready; also drains prologue DMA + all preamble loads

#pragma unroll 1
    for (int t = 0; t < 4; ++t) {
        const int rowW = (tile0 + t) * 512 + wv * 64;    // this wave's 64 rows
        const int r    = rowW + lane;

        f32x4 acc[4][4];
#pragma unroll
        for (int mt = 0; mt < 4; ++mt)
#pragma unroll
            for (int nt = 0; nt < 4; ++nt)
                acc[mt][nt] = f32x4{b1v[nt], b1v[nt], b1v[nt], b1v[nt]};

#pragma unroll
        for (int ks = 0; ks < 4; ++ks) {                 // k0 = ks*32
#pragma unroll
            for (int h = 0; h < 2; ++h) {                // half-step: mt pair {2h,2h+1}
                // ---- issue next chunk's 4 DMAs (into the other buffer) ----
                const int  nh   = h ^ 1;
                const int  nks  = (h == 1) ? ((ks + 1) & 3) : ks;
                const bool bump = (ks == 3 && h == 1);   // crosses into next tile
                if (!bump || t < 3) {
                    const int rowN = (tile0 + t + (bump ? 1 : 0)) * 512 + wv * 64;
#pragma unroll
                    for (int i = 0; i < 4; ++i) {
                        const int mt = 2 * nh + (i >> 1), q16 = i & 1;
                        dma16(slots + (size_t)(rowN + mt * 16 + col) * D
                                    + nks * 32 + quad * 8 + q16 * 4,
                              &stg[nh][wv][i][0][0]);
                    }
                }

                // ---- counted wait: current chunk arrived, next stays in flight.
                if (ks == 0 && h == 0) {
                    if (t == 0) { asm volatile("s_waitcnt vmcnt(4)" ::: "memory"); }
                    else        { asm volatile("s_waitcnt vmcnt(6)" ::: "memory"); }
                } else if (ks == 3 && h == 1) {
                    if (t < 3)  { asm volatile("s_waitcnt vmcnt(4)" ::: "memory"); }
                    else        { asm volatile("s_waitcnt vmcnt(0)" ::: "memory"); }
                } else          { asm volatile("s_waitcnt vmcnt(4)" ::: "memory"); }
                __builtin_amdgcn_sched_barrier(0);

                // ---- read own staged chunk + convert (transient registers) ----
                bf16x8 a1[2], a2[2], a3[2];
#pragma unroll
                for (int mp = 0; mp < 2; ++mp) {
                    const f32x4 va = *(const f32x4*)&stg[h][wv][2 * mp    ][lane][0];
                    const f32x4 vb = *(const f32x4*)&stg[h][wv][2 * mp + 1][lane][0];
                    const float xs[8] = {va[0], va[1], va[2], va[3],
                                         vb[0], vb[1], vb[2], vb[3]};
                    union { int i[4]; bf16x8 vv; } u1, u2, u3;
#pragma unroll
                    for (int p = 0; p < 4; ++p) {
                        unsigned xh1, xh2, xh3, yh1, yh2, yh3;
                        split3(xs[2 * p],     xh1, xh2, xh3);
                        split3(xs[2 * p + 1], yh1, yh2, yh3);
                        u1.i[p] = (int)((xh1 >> 16) | yh1);  // [k even | k odd]
                        u2.i[p] = (int)((xh2 >> 16) | yh2);
                        u3.i[p] = (int)((xh3 >> 16) | yh3);
                    }
                    a1[mp] = u1.vv; a2[mp] = u2.vv; a3[mp] = u3.vv;
                }

                // ---- MFMA: B fragments re-read per-nt (12 live VGPRs only);
                // per-chain accumulation order identical to previous kernel ----
                __builtin_amdgcn_s_setprio(1);
#pragma unroll
                for (int nt = 0; nt < 4; ++nt) {
                    const int j = nt * 16 + col;
                    const int chunk = (ks * 4 + quad) ^ col;
                    const unsigned short* wp = &wt[j * 128 + chunk * 8];
                    const bf16x8 bq1 = *(const bf16x8*)(wp);
                    const bf16x8 bq2 = *(const bf16x8*)(wp + 8192);
                    const bf16x8 bq3 = *(const bf16x8*)(wp + 16384);
#pragma unroll
                    for (int mp = 0; mp < 2; ++mp) {
                        const int mt = 2 * h + mp;
                        f32x4 c = acc[mt][nt];
                        c = __builtin_amdgcn_mfma_f32_16x16x32_bf16(a1[mp], bq1, c, 0, 0, 0);
                        c = __builtin_amdgcn_mfma_f32_16x16x32_bf16(a2[mp], bq1, c, 0, 0, 0);
                        c = __builtin_amdgcn_mfma_f32_16x16x32_bf16(a1[mp], bq2, c, 0, 0, 0);
                        c = __builtin_amdgcn_mfma_f32_16x16x32_bf16(a2[mp], bq2, c, 0, 0, 0);
                        c = __builtin_amdgcn_mfma_f32_16x16x32_bf16(a1[mp], bq3, c, 0, 0, 0);
                        c = __builtin_amdgcn_mfma_f32_16x16x32_bf16(a3[mp], bq1, c, 0, 0, 0);
                        acc[mt][nt] = c;
                    }
                }
                __builtin_amdgcn_s_setprio(0);
            }
        }

        // ---- epilogue: layer2 partials + per-row transpose via LDS ----
        // FULLY UNROLLED over mt: every acc[][] index is compile-time constant
        // so acc stays in the unified VGPR/AGPR file (no scratch demotion).
        // red[wv] is WAVE-PRIVATE; wave LDS ops are in-order -> compile fence only.
        float fl0 = 0.f, fl1 = 0.f;
#pragma unroll
        for (int mt = 0; mt < 4; ++mt) {
#pragma unroll
            for (int reg = 0; reg < 4; ++reg) {
                float p0 = 0.f, p1 = 0.f;
#pragma unroll
                for (int nt = 0; nt < 4; ++nt) {
                    const float h = fmaxf(acc[mt][nt][reg], 0.f);
                    p0 = fmaf(h, w2v[nt].x, p0);
                    p1 = fmaf(h, w2v[nt].y, p1);
                }
                const int rl = quad * 4 + reg;
                *(float2*)&red[wv][rl][col ^ rl][0] = make_float2(p0, p1);
            }
            __builtin_amdgcn_wave_barrier();
            if (quad == mt) {
                const int rl = col;
                float s0 = 0.f, s1 = 0.f;
#pragma unroll
                for (int c = 0; c < 16; ++c) {
                    const float2 vv = *(const float2*)&red[wv][rl][c ^ rl][0];
                    s0 += vv.x; s1 += vv.y;
                }
                fl0 = s0; fl1 = s1;
            }
            __builtin_amdgcn_wave_barrier();
        }
        const float l0 = fl0 + b2v.x;
        const float l1 = fl1 + b2v.y;

        // ---- gumbel decision + keep prob ----
        const float2 guv = (t == 0) ? gu0 : ((t == 1) ? gu1 : ((t == 2) ? gu2 : gu3));
        const float lo = 1e-10f, hi = (float)(1.0 - 1e-7);
        const float u0 = fminf(fmaxf(guv.x, lo), hi);
        const float u1 = fminf(fmaxf(guv.y, lo), hi);
        const float g0 = -logf(-logf(u0));
        const float g1 = -logf(-logf(u1));
        float dec = ((l1 + g1) > (l0 + g0)) ? 1.0f : 0.0f;

        const float m  = fmaxf(l0, l1);
        const float e0 = expf(l0 - m), e1 = expf(l1 - m);
        const float keep = e1 / (e0 + e1);

        // ensure-minimum: this wave's 64 lanes == one b's 64 slots
        const unsigned long long act = __ballot(dec != 0.0f);
        if (act == 0ull) {
            float v = fix_u[r];
            int  idx = lane;
#pragma unroll
            for (int off = 32; off > 0; off >>= 1) {
                const float ov  = __shfl_xor(v, off, 64);
                const int  oidx = __shfl_xor(idx, off, 64);
                if (ov > v || (ov == v && oidx < idx)) { v = ov; idx = oidx; }
            }
            if (lane == idx) dec = 1.0f;
        }

        out[r] = dec;
        out[NROWS + r] = keep;
    }
}

extern "C" void kernel_launch(void* const* d_in, const int* in_sizes, int n_in,
                              void* d_out, int out_size, void* d_ws, size_t ws_size,
                              hipStream_t stream)
{
    const float* slots  = (const float*)d_in[0];
    const float* gumbel = (const float*)d_in[1];
    const float* fixu   = (const float*)d_in[2];
    const float* W1     = (const float*)d_in[3];
    const float* b1     = (const float*)d_in[4];
    const float* W2     = (const float*)d_in[5];
    const float* b2     = (const float*)d_in[6];
    float* out = (float*)d_out;

    gumbel_slot_mfma<<<256, 512, 0, stream>>>(
        slots, gumbel, fixu, W1, b1, W2, b2, out);
}